// Round 5
// baseline (226.985 us; speedup 1.0000x reference)
//
#include <hip/hip_runtime.h>

typedef unsigned short u16;
typedef unsigned int u32;
typedef __attribute__((ext_vector_type(8))) short short8;
typedef __attribute__((ext_vector_type(4))) float floatx4;
typedef __attribute__((ext_vector_type(4))) u32 u32x4;

#define NUMS 2048
#define DIM 128
#define ROWS_TOT 16384
#define HALF_ROWS 8192
#define KTOP 129
#define MTILE 16
#define SCALE 0.08838834764831845f

__device__ __forceinline__ u16 f2bf(float f) {
  u32 u = __builtin_bit_cast(u32, f);
  u += 0x7FFFu + ((u >> 16) & 1u);
  return (u16)(u >> 16);
}
__device__ __forceinline__ float bf2f(u32 b) {
  return __builtin_bit_cast(float, b << 16);
}

// weight fp32 [2048][128] -> wb bf16 [2048][128] (row-major, for GEMM1)
//                         -> wt bf16 [128][2048] (transposed, for GEMM2) with a
// within-32 permutation of the k index:  storage col = (k & ~31) | s,
//   s = 8*((k>>2)&3) + 4*((k>>4)&1) + (k&3)
// s() inverts the chunk-offset map induced by GEMM1's accumulator packing, so
// GEMM2's A-fragment (contiguous short8 at chunk*32 + quad*8) pairs
// element-for-element with a B-fragment that is *exactly* GEMM1's packed
// accumulator registers (no shuffle, no LDS staging of attention).
__global__ void cvt_w_k(const float* __restrict__ w, u16* __restrict__ wb,
                        u16* __restrict__ wt) {
  __shared__ u16 tile[32][33];
  const int tx = threadIdx.x, ty = threadIdx.y;
  const int x = blockIdx.x * 32 + tx;  // col in W (0..127)
  const int y0 = blockIdx.y * 32;      // row block in W
#pragma unroll
  for (int j = 0; j < 32; j += 8) {
    const u16 v = f2bf(w[(size_t)(y0 + ty + j) * DIM + x]);
    wb[(size_t)(y0 + ty + j) * DIM + x] = v;
    tile[ty + j][tx] = v;
  }
  __syncthreads();
  const int k = y0 + tx;  // actual k (row of W = att col)
  const int s = ((k >> 2) & 3) * 8 + ((k >> 4) & 1) * 4 + (k & 3);
  const int x2p = (k & ~31) | s;        // permuted storage col
  const int y2 = blockIdx.x * 32 + ty;  // row in Wt (= col in W)
#pragma unroll
  for (int j = 0; j < 32; j += 8)
    wt[(size_t)(y2 + j) * NUMS + x2p] = tile[tx][ty + j];
}

// Occupancy design (empirical, r0-r4):
//  - __launch_bounds__ arg2 behaves as CUDA min-BLOCKS-per-CU on this toolchain:
//    VGPR cap = 512 / (arg2 * block_waves / 4).  (512,4)->64, (1024,8)->32,
//    (512,2)->128 -- all three confirmed by reported VGPR_Count.
//  - HW wave residency steps at VGPR 64/128/256 (8/4/2 waves per EU).
//    r2 (64 regs, 8-reg spill, 8 w/EU) = 135us BEAT r4 (72 regs, no spill,
//    4 w/EU) = 149us -> residency dominates; must be <=64 regs AND spill-free.
//  - Here: 1024 threads = 16 waves, each owns 128 att cols -> patt[16];
//    peak live ~50 regs. (1024,2) -> 2 blk x 16 waves / 4 = 8 w/EU -> cap 64.
//    => zero spill + 32 waves/CU.
__global__ __launch_bounds__(1024, 2)
void fused_k(const float* __restrict__ dataF, const u16* __restrict__ wb,
             const u16* __restrict__ wt, float* __restrict__ out) {
  __shared__ floatx4 accb4[16 * 32];  // augment accum f32 [16 rows][128 cols], col^row swizzled
  __shared__ u32x4 cntb[16][16];      // per-row, per-wave packed counts (8 u16)
  __shared__ float vbuf[16];          // v* per row
  __shared__ u32 cbuf[16];            // cnt(> v*) per row
  __shared__ u32 basebuf[16];         // probe-window base code per row
  __shared__ float sumbuf[16];        // sum of vals > v* per row
  __shared__ u32 dbuf[16];            // row resolved flag
  __shared__ u32 donecnt;
  float* const accb = (float*)accb4;

  const int tid = threadIdx.x;  // 0..1023
  const int r0 = blockIdx.x * MTILE;
  const int lane = tid & 63;
  const int wave = tid >> 6;  // 0..15
  const int m = lane & 15;
  const int quad = lane >> 4;
  const bool firstHalf = (r0 < HALF_ROWS);

  // ---- init phase ----
  if (firstHalf && tid < 512) accb4[tid] = (floatx4){0.f, 0.f, 0.f, 0.f};
  if (tid < 16) {
    sumbuf[tid] = 0.f;
    dbuf[tid] = 0u;
    basebuf[tid] = 0x3F00u;  // bf16 code of 0.5
  }
  if (tid == 16) donecnt = 0u;
  __syncthreads();  // bar0: zero-init visible before any ds_add

  // ---- B-operand fragments: data rows, fp32 -> bf16 inline ----
  short8 dfrag[4];
  {
    const float* ap = dataF + (r0 + m) * DIM + quad * 8;
#pragma unroll
    for (int ks = 0; ks < 4; ks++) {
      const float4 x = *(const float4*)(ap + ks * 32);
      const float4 y = *(const float4*)(ap + ks * 32 + 4);
      short8 v;
      v[0] = (short)f2bf(x.x); v[1] = (short)f2bf(x.y);
      v[2] = (short)f2bf(x.z); v[3] = (short)f2bf(x.w);
      v[4] = (short)f2bf(y.x); v[5] = (short)f2bf(y.y);
      v[6] = (short)f2bf(y.z); v[7] = (short)f2bf(y.w);
      dfrag[ks] = v;
    }
  }

  // ---- GEMM1 (transposed): att kept in registers ----
  // patt[2t+w] at lane (m,quad) = codes of att[col = wave*128+16t+4q+2w+{0,1}][row m]
  // nt loop MUST stay fully unrolled: every patt[] index literal -> VGPRs only
  // (rule #20: runtime-indexed reg arrays demote to scratch; r1 proved the cost).
  u32 patt[16];
#pragma unroll
  for (int nt = 0; nt < 8; nt++) {
    const int n0 = wave * 128 + nt * 16;
    const u16* wp = wb + (n0 + m) * DIM + quad * 8;
    floatx4 acc = {0.f, 0.f, 0.f, 0.f};
#pragma unroll
    for (int ks = 0; ks < 4; ks++) {
      const short8 wfrag = *(const short8*)(wp + ks * 32);
      acc = __builtin_amdgcn_mfma_f32_16x16x32_bf16(wfrag, dfrag[ks], acc, 0, 0, 0);
    }
    const float a0 = 1.f / (1.f + __expf(-acc[0] * SCALE));
    const float a1 = 1.f / (1.f + __expf(-acc[1] * SCALE));
    const float a2 = 1.f / (1.f + __expf(-acc[2] * SCALE));
    const float a3 = 1.f / (1.f + __expf(-acc[3] * SCALE));
    patt[2 * nt] = (u32)f2bf(a0) | ((u32)f2bf(a1) << 16);
    patt[2 * nt + 1] = (u32)f2bf(a2) | ((u32)f2bf(a3) << 16);
  }

  // ---- first half: read_query = [data_fp32 | attention @ W] ----
  if (firstHalf) {
    if (tid < 512) {  // raw fp32 data -> read_query[:, :128]
      const int row = tid >> 5;
      const int c4 = (tid & 31) << 2;
      *(float4*)(out + 16384 + (size_t)(r0 + row) * 256 + c4) =
          *(const float4*)(dataF + (r0 + row) * DIM + c4);
    }
    // GEMM2: this wave's K-partial (its 128 att cols) for ALL 128 out cols.
    // B operand is patt re-interpreted (wt was k-permuted to match in cvt_w_k).
    // unroll 2: 8 loads in flight + two independent MFMA chains per iteration;
    // patt only indexed by fully-unrolled ks2 -> still static, no scratch.
#pragma unroll 2
    for (int nt2 = 0; nt2 < 8; nt2++) {
      const u16* wtp = wt + (nt2 * 16 + m) * NUMS + wave * 128 + quad * 8;
      floatx4 acc = {0.f, 0.f, 0.f, 0.f};
#pragma unroll
      for (int ks2 = 0; ks2 < 4; ks2++) {
        const short8 a = *(const short8*)(wtp + ks2 * 32);
        const u32x4 bb = {patt[4 * ks2], patt[4 * ks2 + 1],
                          patt[4 * ks2 + 2], patt[4 * ks2 + 3]};
        acc = __builtin_amdgcn_mfma_f32_16x16x32_bf16(
            a, __builtin_bit_cast(short8, bb), acc, 0, 0, 0);
      }
      // D: lane (m,q) holds augment[outcol = 16*nt2+4q+i][row m] K-partial.
      // col^m swizzle keeps the ds_add pattern at worst 4-way.
#pragma unroll
      for (int i = 0; i < 4; i++) {
        const int oc = nt2 * 16 + quad * 4 + i;
        atomicAdd(accb + m * 128 + (oc ^ m), acc[i]);
      }
    }
  }

  // ---- top-129 per row: SWAR counts at 8 consecutive bf16 codes ----
  const u32 M8 = 0x80008000u;
  auto count_pub = [&](u32 base) {
    u32 pk[4];
#pragma unroll
    for (int j = 0; j < 4; j++) {
      // (code | 0x8000) - t  ==  code + (0x8000 - t): no cross-half carry
      const u32 uA = M8 - (base + 2u * j) * 0x10001u;
      const u32 uB = uA - 0x10001u;
      u32 cA = 0, cB = 0;
#pragma unroll
      for (int i = 0; i < 16; i++) {
        cA += __popc((patt[i] + uA) & M8);
        cB += __popc((patt[i] + uB) & M8);
      }
      pk[j] = cA | (cB << 16);
    }
#pragma unroll
    for (int j = 0; j < 4; j++) {  // sum the 4 quads of row m
      pk[j] += __shfl_xor(pk[j], 16);
      pk[j] += __shfl_xor(pk[j], 32);
    }
    if (quad == 0)  // wave^(m&15) slot swizzle: spreads the b128 writes
      cntb[m][wave ^ (m & 15)] = (u32x4){pk[0], pk[1], pk[2], pk[3]};
  };

  auto resolve = [&]() {
    const int rr = wave;   // one wave per row; 64 lanes reduce 16 wave-partials
    if (dbuf[rr]) return;  // wave-uniform
    const u32 base = basebuf[rr];
    u32x4 c = cntb[rr][(lane & 15) ^ (rr & 15)];
    u32 p0 = c.x, p1 = c.y, p2 = c.z, p3 = c.w;
#pragma unroll
    for (int off = 1; off < 16; off <<= 1) {  // sum 16 wave-partials
      p0 += __shfl_xor(p0, off);
      p1 += __shfl_xor(p1, off);
      p2 += __shfl_xor(p2, off);
      p3 += __shfl_xor(p3, off);
    }
    const int cw0 = (int)(p0 & 0xFFFFu), cw1 = (int)(p0 >> 16);
    const int cw2 = (int)(p1 & 0xFFFFu), cw3 = (int)(p1 >> 16);
    const int cw4 = (int)(p2 & 0xFFFFu), cw5 = (int)(p2 >> 16);
    const int cw6 = (int)(p3 & 0xFFFFu), cw7 = (int)(p3 >> 16);
    if (cw0 >= KTOP && cw7 < KTOP) {  // 129th value inside window
      const int idx = (cw1 >= KTOP) + (cw2 >= KTOP) + (cw3 >= KTOP) +
                      (cw4 >= KTOP) + (cw5 >= KTOP) + (cw6 >= KTOP) +
                      (cw7 >= KTOP);
      // cgt = cw[idx+1] = largest count < KTOP (counts monotone nonincreasing)
      int cgt = 0;
      cgt = (cw1 < KTOP && cw1 > cgt) ? cw1 : cgt;
      cgt = (cw2 < KTOP && cw2 > cgt) ? cw2 : cgt;
      cgt = (cw3 < KTOP && cw3 > cgt) ? cw3 : cgt;
      cgt = (cw4 < KTOP && cw4 > cgt) ? cw4 : cgt;
      cgt = (cw5 < KTOP && cw5 > cgt) ? cw5 : cgt;
      cgt = (cw6 < KTOP && cw6 > cgt) ? cw6 : cgt;
      cgt = (cw7 < KTOP && cw7 > cgt) ? cw7 : cgt;
      if (lane == 0) {
        vbuf[rr] = bf2f(base + (u32)idx);
        cbuf[rr] = (u32)cgt;
        dbuf[rr] = 1u;
        atomicAdd(&donecnt, 1u);
      }
    } else if (lane == 0) {  // cold: slide the window (never in practice)
      basebuf[rr] = (cw0 < KTOP) ? base - 7u : base + 7u;
    }
  };

  count_pub(0x3F00u);
  __syncthreads();  // bar1: counts published
  resolve();
  __syncthreads();  // bar2: v*/cgt published (or base adjusted)
  while (donecnt < 16u) {  // cold re-probe loop, block-uniform
    count_pub(basebuf[m]);
    __syncthreads();
    resolve();
    __syncthreads();
  }

  // ---- exact top-K sum: sum(vals > v*) + (K - cgt) * v* ----
  {
    const float vst = vbuf[m];
    float s = 0.f;
#pragma unroll
    for (int i = 0; i < 16; i++) {
      const float v0 = bf2f(patt[i] & 0xFFFFu);
      const float v1 = __builtin_bit_cast(float, patt[i] & 0xFFFF0000u);
      if (v0 > vst) s += v0;
      if (v1 > vst) s += v1;
    }
    s += __shfl_xor(s, 16);
    s += __shfl_xor(s, 32);
    if (quad == 0) atomicAdd(&sumbuf[m], s);
  }
  __syncthreads();  // bar3: sums + augment accumulation complete

  if (tid < 16) {
    const float mean = (sumbuf[tid] + (float)(KTOP - (int)cbuf[tid]) * vbuf[tid]) *
                       (1.f / (float)KTOP);
    out[r0 + tid] = 1.f - mean;
  }
  if (firstHalf && tid < 512) {  // augment: unswizzle accbuf -> read_query[:, 128:256]
    const int row = tid >> 5;
    const int c = tid & 31;
    const int r = row & 3;
    floatx4 v = *((floatx4*)(accb + row * 128 + 4 * (c ^ (row >> 2))));
    if (r & 1) { float t = v[0]; v[0] = v[1]; v[1] = t; t = v[2]; v[2] = v[3]; v[3] = t; }
    if (r & 2) { float t = v[0]; v[0] = v[2]; v[2] = t; t = v[1]; v[1] = v[3]; v[3] = t; }
    *(float4*)(out + 16384 + (size_t)(r0 + row) * 256 + 128 + 4 * c) =
        (float4){v[0], v[1], v[2], v[3]};
  }
}

extern "C" void kernel_launch(void* const* d_in, const int* in_sizes, int n_in,
                              void* d_out, int out_size, void* d_ws, size_t ws_size,
                              hipStream_t stream) {
  const float* data = (const float*)d_in[0];    // [32,512,128] fp32
  const float* weight = (const float*)d_in[1];  // [2048,128] fp32
  float* out = (float*)d_out;  // 16384 mem_score + 16*512*256 read_query (fp32)

  u16* wt = (u16*)d_ws;       // [128][2048] bf16 (k-permuted), 512 KiB
  u16* wb = wt + NUMS * DIM;  // [2048][128] bf16, 512 KiB

  cvt_w_k<<<dim3(DIM / 32, NUMS / 32), dim3(32, 8), 0, stream>>>(weight, wb, wt);
  fused_k<<<dim3(ROWS_TOT / MTILE), dim3(1024), 0, stream>>>(data, wb, wt, out);
}

// Round 6
// 169.334 us; speedup vs baseline: 1.3405x; 1.3405x over previous
//
#include <hip/hip_runtime.h>

typedef unsigned short u16;
typedef unsigned int u32;
typedef __attribute__((ext_vector_type(8))) short short8;
typedef __attribute__((ext_vector_type(4))) float floatx4;

#define NUMS 2048
#define DIM 128
#define ROWS_TOT 16384
#define HALF_ROWS 8192
#define KTOP 129
#define MTILE 32
#define SP 2056  // padded S row stride (elems): breaks bank alignment, keeps b64/b128 alignment
#define SCALE 0.08838834764831845f

__device__ __forceinline__ u16 f2bf(float f) {
  u32 u = __builtin_bit_cast(u32, f);
  u += 0x7FFFu + ((u >> 16) & 1u);
  return (u16)(u >> 16);
}
__device__ __forceinline__ float bf2f(u32 b) {
  return __builtin_bit_cast(float, b << 16);
}

// weight fp32 [2048][128] -> wb bf16 [2048][128] + wt bf16 [128][2048] (plain
// transpose; GEMM2's B operand comes from the LDS S tile again, so no k-perm).
__global__ void cvt_w_k(const float* __restrict__ w, u16* __restrict__ wb,
                        u16* __restrict__ wt) {
  __shared__ u16 tile[32][33];
  const int tx = threadIdx.x, ty = threadIdx.y;
  const int x = blockIdx.x * 32 + tx;  // col in W (0..127)
  const int y0 = blockIdx.y * 32;      // row block in W
#pragma unroll
  for (int j = 0; j < 32; j += 8) {
    const u16 v = f2bf(w[(size_t)(y0 + ty + j) * DIM + x]);
    wb[(size_t)(y0 + ty + j) * DIM + x] = v;
    tile[ty + j][tx] = v;
  }
  __syncthreads();
  const int x2 = y0 + tx;               // col in Wt (= row in W)
  const int y2 = blockIdx.x * 32 + ty;  // row in Wt (= col in W)
#pragma unroll
  for (int j = 0; j < 32; j += 8)
    wt[(size_t)(y2 + j) * NUMS + x2] = tile[tx][ty + j];
}

// r6 design: r0's proven structure (LDS S tile, 1 barrier, full-K GEMM2 per
// wave, in-wave topk) scaled to MTILE=32 / 1024 threads / 16 waves:
//   - wave = (row-group rg = wave>>3) x (col-slice ws = wave&7);
//     per-wave tile shapes IDENTICAL to r0 (16 rows x 256 att-cols, 64-MFMA
//     GEMM1 chain; 16 out-cols x full K=2048 GEMM2 chain).
//   - blocks 1024->512: per-CU L2 weight streaming halves (4->2 MB) -- the
//     measured bottleneck of the r0 family.
//   - LDS 131.6 KB -> 1 block/CU = 16 waves/CU (the de-facto residency every
//     variant r0-r5 achieved anyway; reg-resident designs that chased 32
//     waves/CU all lost on per-wave MLP).
//   - (1024,1): VGPR cap 128 (arg2 = min BLOCKS/CU on this toolchain,
//     confirmed r0-r5), so loads can be hoisted (r0 was squeezed at cap 64).
__global__ __launch_bounds__(1024, 1)
void fused_k(const float* __restrict__ dataF, const u16* __restrict__ wb,
             const u16* __restrict__ wt, float* __restrict__ out) {
  __shared__ u16 S[MTILE * SP];  // 131,584 B: att tile, S[data-row][att-col]
  const int tid = threadIdx.x;  // 0..1023
  const int r0 = blockIdx.x * MTILE;
  const int lane = tid & 63;
  const int wave = tid >> 6;  // 0..15
  const int rg = wave >> 3;   // row-group (16 rows each)
  const int ws = wave & 7;    // att-col slice (256 cols each)
  const int m = lane & 15;
  const int quad = lane >> 4;

  // ---- B-operand fragments: data rows, fp32 -> bf16 inline ----
  short8 dfrag[4];
  {
    const float* ap = dataF + (size_t)(r0 + rg * 16 + m) * DIM + quad * 8;
#pragma unroll
    for (int ks = 0; ks < 4; ks++) {
      const float4 x = *(const float4*)(ap + ks * 32);
      const float4 y = *(const float4*)(ap + ks * 32 + 4);
      short8 v;
      v[0] = (short)f2bf(x.x); v[1] = (short)f2bf(x.y);
      v[2] = (short)f2bf(x.z); v[3] = (short)f2bf(x.w);
      v[4] = (short)f2bf(y.x); v[5] = (short)f2bf(y.y);
      v[6] = (short)f2bf(y.z); v[7] = (short)f2bf(y.w);
      dfrag[ks] = v;
    }
  }

  // ---- GEMM1 (transposed): D[att-col][data-row] = W * data^T ----
  // C-layout: lane holds data-row = rg*16+m, att-cols = n0 + quad*4 + {0..3}
  u16* sbase = S + (rg * 16 + m) * SP + ws * 256 + quad * 4;
#pragma unroll
  for (int nt = 0; nt < 16; nt++) {
    const int n0 = ws * 256 + nt * 16;
    const u16* wp = wb + (size_t)(n0 + m) * DIM + quad * 8;
    floatx4 acc = {0.f, 0.f, 0.f, 0.f};
#pragma unroll
    for (int ks = 0; ks < 4; ks++) {
      const short8 wfrag = *(const short8*)(wp + ks * 32);
      acc = __builtin_amdgcn_mfma_f32_16x16x32_bf16(wfrag, dfrag[ks], acc, 0, 0, 0);
    }
    float a0 = 1.f / (1.f + __expf(-acc[0] * SCALE));
    float a1 = 1.f / (1.f + __expf(-acc[1] * SCALE));
    float a2 = 1.f / (1.f + __expf(-acc[2] * SCALE));
    float a3 = 1.f / (1.f + __expf(-acc[3] * SCALE));
    uint2 p;
    p.x = (u32)f2bf(a0) | ((u32)f2bf(a1) << 16);
    p.y = (u32)f2bf(a2) | ((u32)f2bf(a3) << 16);
    *(uint2*)(sbase + nt * 16) = p;  // 4 consecutive att-cols, one b64 write
  }
  __syncthreads();  // the ONE barrier: S complete

  // ---- first half: read_query = [data_fp32 | attention @ W] ----
  if (r0 < HALF_ROWS) {
    {  // copy fp32 data -> read_query[:, :128]
      const int row = tid >> 5;          // 0..31
      const int c4 = (tid & 31) << 2;
      *(float4*)(out + 16384 + (size_t)(r0 + row) * 256 + c4) =
          *(const float4*)(dataF + (size_t)(r0 + row) * DIM + c4);
    }
    // GEMM2 (transposed): D[out-col][data-row] = W^T * att^T, full K=2048.
    // A-frag: wt rows (out-cols n2+m), B-frag: S rows (att of data-row rg*16+m)
    const int n2 = ws * 16;
    const u16* wtp = wt + (size_t)(n2 + m) * NUMS + quad * 8;
    const u16* sp2 = S + (rg * 16 + m) * SP + quad * 8;
    floatx4 acc = {0.f, 0.f, 0.f, 0.f};
#pragma unroll 8
    for (int ks = 0; ks < 64; ks++) {
      const short8 a = *(const short8*)(wtp + ks * 32);  // imm offsets ks*64B
      const short8 b = *(const short8*)(sp2 + ks * 32);
      acc = __builtin_amdgcn_mfma_f32_16x16x32_bf16(a, b, acc, 0, 0, 0);
    }
    // lane: data-row rg*16+m, out-cols n2 + quad*4 + {0..3} -> one dwordx4
    float4 st;
    st.x = acc[0]; st.y = acc[1]; st.z = acc[2]; st.w = acc[3];
    *(float4*)(out + 16384 + (size_t)(r0 + rg * 16 + m) * 256 + 128 + n2 + quad * 4) = st;
  }

  // ---- top-129 mean per row -> mem_score = 1 - mean ----
#pragma unroll
  for (int rv = 0; rv < 2; rv++) {
    const int rr = wave * 2 + rv;  // 16 waves x 2 = 32 rows
    const u16* rp = S + rr * SP + lane * 8;  // 16 B per lane per chunk
    u32 x[16], xh[16];
#pragma unroll
    for (int j = 0; j < 4; j++) {
      const short8 v = *(const short8*)(rp + j * 512);
      const u32* pv = (const u32*)&v;
      x[j * 4 + 0] = pv[0]; x[j * 4 + 1] = pv[1];
      x[j * 4 + 2] = pv[2]; x[j * 4 + 3] = pv[3];
    }
#pragma unroll
    for (int i = 0; i < 16; i++) xh[i] = x[i] | 0x80008000u;

    // per-lane count of (bf16 code >= t), two codes per dword (SWAR)
    auto cnt_ge = [&](u32 t) -> int {
      const u32 t2 = t * 0x10001u;
      int c = 0;
#pragma unroll
      for (int i = 0; i < 16; i++)
        c += __popc((xh[i] - t2) & 0x80008000u);
      return c;
    };

    // 8 independent counts at consecutive codes 0x3F00..0x3F07 (atts ~0.5+-0.06)
    int c8[8];
#pragma unroll
    for (int j = 0; j < 8; j++) c8[j] = cnt_ge(0x3F00u + (u32)j);
    u32 pk[4];
#pragma unroll
    for (int j = 0; j < 4; j++) pk[j] = (u32)c8[2 * j] | ((u32)c8[2 * j + 1] << 16);
#pragma unroll
    for (int off = 1; off < 64; off <<= 1) {
#pragma unroll
      for (int j = 0; j < 4; j++) pk[j] += __shfl_xor(pk[j], off);
    }
    int cw[8];
#pragma unroll
    for (int j = 0; j < 4; j++) {
      cw[2 * j] = (int)(pk[j] & 0xFFFFu);
      cw[2 * j + 1] = (int)(pk[j] >> 16);
    }

    u32 lo;
    int cgt;
    if (cw[0] >= KTOP && cw[7] < KTOP) {  // 129th value inside the window
      int idx = 0;
#pragma unroll
      for (int j = 1; j < 8; j++) idx += (cw[j] >= KTOP) ? 1 : 0;  // counts monotone
      lo = 0x3F00u + (u32)idx;
      cgt = cw[idx + 1];  // idx <= 6 guaranteed by window test
    } else {  // fallback: full binary search over bf16 codes (cold, never in practice)
      u32 L = 0u, H = 0x3F81u;
      while (H - L > 1u) {
        const u32 mid = (L + H) >> 1;
        int cc = cnt_ge(mid);
#pragma unroll
        for (int off = 1; off < 64; off <<= 1) cc += __shfl_xor(cc, off);
        if (cc >= KTOP) L = mid; else H = mid;
      }
      lo = L;
      int cg = cnt_ge(lo + 1);
#pragma unroll
      for (int off = 1; off < 64; off <<= 1) cg += __shfl_xor(cg, off);
      cgt = cg;
    }

    // exact top-K sum: sum(vals > v*) + (K - cnt_gt) * v*
    const float vstar = bf2f(lo);
    float s = 0.f;
#pragma unroll
    for (int i = 0; i < 16; i++) {
      const float v0 = bf2f(x[i] & 0xFFFFu);
      const float v1 = __builtin_bit_cast(float, x[i] & 0xFFFF0000u);
      if (v0 > vstar) s += v0;
      if (v1 > vstar) s += v1;
    }
#pragma unroll
    for (int off = 1; off < 64; off <<= 1) s += __shfl_xor(s, off);
    if (lane == 0) {
      const float mean = (s + (float)(KTOP - cgt) * vstar) * (1.f / (float)KTOP);
      out[r0 + rr] = 1.f - mean;
    }
  }
}

extern "C" void kernel_launch(void* const* d_in, const int* in_sizes, int n_in,
                              void* d_out, int out_size, void* d_ws, size_t ws_size,
                              hipStream_t stream) {
  const float* data = (const float*)d_in[0];    // [32,512,128] fp32
  const float* weight = (const float*)d_in[1];  // [2048,128] fp32
  float* out = (float*)d_out;  // 16384 mem_score + 16*512*256 read_query (fp32)

  u16* wt = (u16*)d_ws;       // [128][2048] bf16, 512 KiB
  u16* wb = wt + NUMS * DIM;  // [2048][128] bf16, 512 KiB

  cvt_w_k<<<dim3(DIM / 32, NUMS / 32), dim3(32, 8), 0, stream>>>(weight, wb, wt);
  fused_k<<<dim3(ROWS_TOT / MTILE), dim3(1024), 0, stream>>>(data, wb, wt, out);
}

// Round 7
// 162.069 us; speedup vs baseline: 1.4005x; 1.0448x over previous
//
#include <hip/hip_runtime.h>

typedef unsigned short u16;
typedef unsigned int u32;
typedef __attribute__((ext_vector_type(8))) short short8;
typedef __attribute__((ext_vector_type(4))) float floatx4;

#define NUMS 2048
#define DIM 128
#define ROWS_TOT 16384
#define HALF_ROWS 8192
#define KTOP 129
#define MTILE 16
#define SP 2056  // padded S row stride (elems): breaks bank alignment, keeps b64/b128 alignment
#define SCALE 0.08838834764831845f

__device__ __forceinline__ u16 f2bf(float f) {
  u32 u = __builtin_bit_cast(u32, f);
  u += 0x7FFFu + ((u >> 16) & 1u);
  return (u16)(u >> 16);
}
__device__ __forceinline__ float bf2f(u32 b) {
  return __builtin_bit_cast(float, b << 16);
}

// weight fp32 [2048][128] -> wb bf16 [2048][128] + wt bf16 [128][2048]
__global__ void cvt_w_k(const float* __restrict__ w, u16* __restrict__ wb,
                        u16* __restrict__ wt) {
  __shared__ u16 tile[32][33];
  const int tx = threadIdx.x, ty = threadIdx.y;
  const int x = blockIdx.x * 32 + tx;  // col in W (0..127)
  const int y0 = blockIdx.y * 32;      // row block in W
#pragma unroll
  for (int j = 0; j < 32; j += 8) {
    const u16 v = f2bf(w[(size_t)(y0 + ty + j) * DIM + x]);
    wb[(size_t)(y0 + ty + j) * DIM + x] = v;
    tile[ty + j][tx] = v;
  }
  __syncthreads();
  const int x2 = y0 + tx;               // col in Wt (= row in W)
  const int y2 = blockIdx.x * 32 + ty;  // row in Wt (= col in W)
#pragma unroll
  for (int j = 0; j < 32; j += 8)
    wt[(size_t)(y2 + j) * NUMS + x2] = tile[tx][ty + j];
}

// r7 = r0's champion structure (113us) + per-wave ILP:
//   - GEMM2: 4 independent accumulators -> serial MFMA dep chain 64 -> 16.
//   - GEMM1: 2 nt-tiles in flight (2 accs, interleaved MFMA, shared dfrag).
//   - (512,2): VGPR cap 128 (arg2 = min BLOCKS/CU on this toolchain, r0-r5
//     confirmed). Occupancy is LDS-capped (66KB -> 2 blocks/CU = 16 waves/CU)
//     so the higher reg cap is free; it lets the compiler hold the pipeline.
// Theory: all 7 prior configs pin at ~16 waves/CU and dur >> all throughput
// floors -> latency-bound at fixed TLP; the serial acc chains are the stall.
__global__ __launch_bounds__(512, 2)
void fused_k(const float* __restrict__ dataF, const u16* __restrict__ wb,
             const u16* __restrict__ wt, float* __restrict__ out) {
  __shared__ u16 S[MTILE * SP];  // 65792 B: att tile, S[data-row][att-col]
  const int tid = threadIdx.x;
  const int r0 = blockIdx.x * MTILE;
  const int lane = tid & 63;
  const int wave = tid >> 6;  // 0..7
  const int m = lane & 15;
  const int quad = lane >> 4;

  // ---- B-operand fragments: data rows, fp32 -> bf16 inline ----
  short8 dfrag[4];
  {
    const float* ap = dataF + (size_t)(r0 + m) * DIM + quad * 8;
#pragma unroll
    for (int ks = 0; ks < 4; ks++) {
      const float4 x = *(const float4*)(ap + ks * 32);
      const float4 y = *(const float4*)(ap + ks * 32 + 4);
      short8 v;
      v[0] = (short)f2bf(x.x); v[1] = (short)f2bf(x.y);
      v[2] = (short)f2bf(x.z); v[3] = (short)f2bf(x.w);
      v[4] = (short)f2bf(y.x); v[5] = (short)f2bf(y.y);
      v[6] = (short)f2bf(y.z); v[7] = (short)f2bf(y.w);
      dfrag[ks] = v;
    }
  }

  // ---- GEMM1 (transposed): D[att-col][data-row] = W * data^T ----
  // C-layout: lane holds data-row = m, att-cols = n0 + quad*4 + {0..3}.
  // 2 nt-tiles per iteration: 8 loads + 8 MFMAs in flight, 2 sigmoid
  // epilogues per iter overlap the next pair's loads.
  u16* sbase = S + m * SP + wave * 256 + quad * 4;
#pragma unroll
  for (int np = 0; np < 8; np++) {
    const int n0 = wave * 256 + np * 32;
    const u16* wpA = wb + (size_t)(n0 + m) * DIM + quad * 8;
    const u16* wpB = wpA + 16 * DIM;  // next 16 att-cols
    floatx4 accA = {0.f, 0.f, 0.f, 0.f};
    floatx4 accB = {0.f, 0.f, 0.f, 0.f};
#pragma unroll
    for (int ks = 0; ks < 4; ks++) {
      const short8 wfA = *(const short8*)(wpA + ks * 32);
      const short8 wfB = *(const short8*)(wpB + ks * 32);
      accA = __builtin_amdgcn_mfma_f32_16x16x32_bf16(wfA, dfrag[ks], accA, 0, 0, 0);
      accB = __builtin_amdgcn_mfma_f32_16x16x32_bf16(wfB, dfrag[ks], accB, 0, 0, 0);
    }
    {
      const float a0 = 1.f / (1.f + __expf(-accA[0] * SCALE));
      const float a1 = 1.f / (1.f + __expf(-accA[1] * SCALE));
      const float a2 = 1.f / (1.f + __expf(-accA[2] * SCALE));
      const float a3 = 1.f / (1.f + __expf(-accA[3] * SCALE));
      uint2 p;
      p.x = (u32)f2bf(a0) | ((u32)f2bf(a1) << 16);
      p.y = (u32)f2bf(a2) | ((u32)f2bf(a3) << 16);
      *(uint2*)(sbase + np * 32) = p;
    }
    {
      const float a0 = 1.f / (1.f + __expf(-accB[0] * SCALE));
      const float a1 = 1.f / (1.f + __expf(-accB[1] * SCALE));
      const float a2 = 1.f / (1.f + __expf(-accB[2] * SCALE));
      const float a3 = 1.f / (1.f + __expf(-accB[3] * SCALE));
      uint2 p;
      p.x = (u32)f2bf(a0) | ((u32)f2bf(a1) << 16);
      p.y = (u32)f2bf(a2) | ((u32)f2bf(a3) << 16);
      *(uint2*)(sbase + np * 32 + 16) = p;
    }
  }
  __syncthreads();  // the ONE barrier: S complete

  // ---- first half: read_query = [data_fp32 | attention @ W] ----
  if (r0 < HALF_ROWS) {
    {  // copy fp32 data -> read_query[:, :128]
      const int row = tid >> 5;
      const int c4 = (tid & 31) << 2;
      *(float4*)(out + 16384 + (size_t)(r0 + row) * 256 + c4) =
          *(const float4*)(dataF + (size_t)(r0 + row) * DIM + c4);
    }
    // GEMM2 (transposed): D[out-col][data-row] = W^T * att^T, full K=2048.
    // 4 independent accumulators: dep chain 64 -> 16 MFMA; 8 loads/step.
    const int n2 = wave * 16;
    const u16* wtp = wt + (size_t)(n2 + m) * NUMS + quad * 8;
    const u16* sp2 = S + m * SP + quad * 8;
    floatx4 ac0 = {0.f, 0.f, 0.f, 0.f};
    floatx4 ac1 = {0.f, 0.f, 0.f, 0.f};
    floatx4 ac2 = {0.f, 0.f, 0.f, 0.f};
    floatx4 ac3 = {0.f, 0.f, 0.f, 0.f};
#pragma unroll
    for (int kb = 0; kb < 16; kb++) {
      const short8 a0 = *(const short8*)(wtp + (kb * 4 + 0) * 32);
      const short8 b0 = *(const short8*)(sp2 + (kb * 4 + 0) * 32);
      const short8 a1 = *(const short8*)(wtp + (kb * 4 + 1) * 32);
      const short8 b1 = *(const short8*)(sp2 + (kb * 4 + 1) * 32);
      const short8 a2 = *(const short8*)(wtp + (kb * 4 + 2) * 32);
      const short8 b2 = *(const short8*)(sp2 + (kb * 4 + 2) * 32);
      const short8 a3 = *(const short8*)(wtp + (kb * 4 + 3) * 32);
      const short8 b3 = *(const short8*)(sp2 + (kb * 4 + 3) * 32);
      ac0 = __builtin_amdgcn_mfma_f32_16x16x32_bf16(a0, b0, ac0, 0, 0, 0);
      ac1 = __builtin_amdgcn_mfma_f32_16x16x32_bf16(a1, b1, ac1, 0, 0, 0);
      ac2 = __builtin_amdgcn_mfma_f32_16x16x32_bf16(a2, b2, ac2, 0, 0, 0);
      ac3 = __builtin_amdgcn_mfma_f32_16x16x32_bf16(a3, b3, ac3, 0, 0, 0);
    }
    const floatx4 accs = (ac0 + ac1) + (ac2 + ac3);
    // lane: data-row m, out-cols n2 + quad*4 + {0..3} -> one dwordx4 store
    float4 st;
    st.x = accs[0]; st.y = accs[1]; st.z = accs[2]; st.w = accs[3];
    *(float4*)(out + 16384 + (size_t)(r0 + m) * 256 + 128 + n2 + quad * 4) = st;
  }

  // ---- top-129 mean per row -> mem_score = 1 - mean ----
#pragma unroll
  for (int rv = 0; rv < 2; rv++) {
    const int rr = wave * 2 + rv;
    const u16* rp = S + rr * SP + lane * 8;  // 16 B per lane per chunk
    u32 x[16], xh[16];
#pragma unroll
    for (int j = 0; j < 4; j++) {
      const short8 v = *(const short8*)(rp + j * 512);
      const u32* pv = (const u32*)&v;
      x[j * 4 + 0] = pv[0]; x[j * 4 + 1] = pv[1];
      x[j * 4 + 2] = pv[2]; x[j * 4 + 3] = pv[3];
    }
#pragma unroll
    for (int i = 0; i < 16; i++) xh[i] = x[i] | 0x80008000u;

    // per-lane count of (bf16 code >= t), two codes per dword (SWAR)
    auto cnt_ge = [&](u32 t) -> int {
      const u32 t2 = t * 0x10001u;
      int c = 0;
#pragma unroll
      for (int i = 0; i < 16; i++)
        c += __popc((xh[i] - t2) & 0x80008000u);
      return c;
    };

    // 8 independent counts at consecutive codes 0x3F00..0x3F07 (atts ~0.5+-0.06)
    int c8[8];
#pragma unroll
    for (int j = 0; j < 8; j++) c8[j] = cnt_ge(0x3F00u + (u32)j);
    u32 pk[4];
#pragma unroll
    for (int j = 0; j < 4; j++) pk[j] = (u32)c8[2 * j] | ((u32)c8[2 * j + 1] << 16);
#pragma unroll
    for (int off = 1; off < 64; off <<= 1) {
#pragma unroll
      for (int j = 0; j < 4; j++) pk[j] += __shfl_xor(pk[j], off);
    }
    int cw[8];
#pragma unroll
    for (int j = 0; j < 4; j++) {
      cw[2 * j] = (int)(pk[j] & 0xFFFFu);
      cw[2 * j + 1] = (int)(pk[j] >> 16);
    }

    u32 lo;
    int cgt;
    if (cw[0] >= KTOP && cw[7] < KTOP) {  // 129th value inside the window
      int idx = 0;
#pragma unroll
      for (int j = 1; j < 8; j++) idx += (cw[j] >= KTOP) ? 1 : 0;  // counts monotone
      lo = 0x3F00u + (u32)idx;
      cgt = cw[idx + 1];  // idx <= 6 guaranteed by window test
    } else {  // fallback: full binary search over bf16 codes (cold, never in practice)
      u32 L = 0u, H = 0x3F81u;
      while (H - L > 1u) {
        const u32 mid = (L + H) >> 1;
        int cc = cnt_ge(mid);
#pragma unroll
        for (int off = 1; off < 64; off <<= 1) cc += __shfl_xor(cc, off);
        if (cc >= KTOP) L = mid; else H = mid;
      }
      lo = L;
      int cg = cnt_ge(lo + 1);
#pragma unroll
      for (int off = 1; off < 64; off <<= 1) cg += __shfl_xor(cg, off);
      cgt = cg;
    }

    // exact top-K sum: sum(vals > v*) + (K - cnt_gt) * v*
    const float vstar = bf2f(lo);
    float s = 0.f;
#pragma unroll
    for (int i = 0; i < 16; i++) {
      const float v0 = bf2f(x[i] & 0xFFFFu);
      const float v1 = __builtin_bit_cast(float, x[i] & 0xFFFF0000u);
      if (v0 > vstar) s += v0;
      if (v1 > vstar) s += v1;
    }
#pragma unroll
    for (int off = 1; off < 64; off <<= 1) s += __shfl_xor(s, off);
    if (lane == 0) {
      const float mean = (s + (float)(KTOP - cgt) * vstar) * (1.f / (float)KTOP);
      out[r0 + rr] = 1.f - mean;
    }
  }
}

extern "C" void kernel_launch(void* const* d_in, const int* in_sizes, int n_in,
                              void* d_out, int out_size, void* d_ws, size_t ws_size,
                              hipStream_t stream) {
  const float* data = (const float*)d_in[0];    // [32,512,128] fp32
  const float* weight = (const float*)d_in[1];  // [2048,128] fp32
  float* out = (float*)d_out;  // 16384 mem_score + 16*512*256 read_query (fp32)

  u16* wt = (u16*)d_ws;       // [128][2048] bf16, 512 KiB
  u16* wb = wt + NUMS * DIM;  // [2048][128] bf16, 512 KiB

  cvt_w_k<<<dim3(DIM / 32, NUMS / 32), dim3(32, 8), 0, stream>>>(weight, wb, wt);
  fused_k<<<dim3(ROWS_TOT / MTILE), dim3(512), 0, stream>>>(data, wb, wt, out);
}